// Round 5
// baseline (209.726 us; speedup 1.0000x reference)
//
#include <hip/hip_runtime.h>

// Y: 16384 x 2048 fp32 row-major. loss = sum_c |1 - (1/n) * sum_r Y[r][c]^2|
#define NROWS 16384
#define D     2048
#define D4    (D / 4)                 // 512 float4 per row
#define K1BLK 2048
#define GSZ   (K1BLK * 256)           // 524288 threads; 524288 % 512 == 0
#define ITERS (NROWS * D4 / GSZ)      // 16
#define STRIPES (GSZ / D4)            // 1024 stripes of partials
#define K2BLK 32

// K1: whole-grid lockstep sweep. Iteration i: thread g loads Y4[g + i*GSZ]
// -- the entire grid reads one contiguous, forward-moving 32MB window
// (fill/copy-benchmark pattern). Since GSZ % D4 == 0, thread g always hits
// float4-column g & 511, so its accumulator maps to 4 fixed columns.
// P4[g] holds that partial; as floats P is [STRIPES][D] with col = idx & 2047.
__global__ void __launch_bounds__(256)
colsq_sweep(const float4* __restrict__ Y4, float4* __restrict__ P4) {
    const int g = blockIdx.x * 256 + threadIdx.x;
    const float4* p = Y4 + g;
    float4 a = make_float4(0.f, 0.f, 0.f, 0.f);
#pragma unroll
    for (int i = 0; i < ITERS; ++i) {
        float4 v = p[(size_t)i * GSZ];
        a.x += v.x * v.x;
        a.y += v.y * v.y;
        a.z += v.z * v.z;
        a.w += v.w * v.w;
    }
    P4[g] = a;
}

// K2: reduce 1024 stripes per column, |1 - s/n|, block-reduce 64 cols,
// then counter-elect the last of 32 blocks to sum the 32 partials -> out.
// Block b owns cols [b*64, b*64+64); 4 threads/col, each sums 256 stripes.
__global__ void __launch_bounds__(256)
col_finalize(const float* __restrict__ P, float* __restrict__ ws2,
             unsigned* __restrict__ counter, float* __restrict__ out) {
    const int tid  = threadIdx.x;
    const int col  = blockIdx.x * 64 + (tid & 63);
    const int part = tid >> 6;                      // 0..3
    float s = 0.f;
#pragma unroll 8
    for (int i = 0; i < STRIPES / 4; ++i) {
        int yb = part * (STRIPES / 4) + i;
        s += P[(size_t)yb * D + col];
    }
    __shared__ float lds[256];
    lds[tid] = s;
    __syncthreads();
    if (tid < 64) {
        float tot = lds[tid] + lds[tid + 64] + lds[tid + 128] + lds[tid + 192];
        float v = fabsf(1.0f - tot * (1.0f / (float)NROWS));
#pragma unroll
        for (int off = 32; off; off >>= 1)
            v += __shfl_down(v, off, 64);
        if (tid == 0) ws2[blockIdx.x] = v;
    }
    // completion counter: one agent-scope RMW per block (32 total)
    __threadfence();
    __shared__ int is_last;
    if (tid == 0) {
        unsigned old = __hip_atomic_fetch_add(counter, 1u, __ATOMIC_ACQ_REL,
                                              __HIP_MEMORY_SCOPE_AGENT);
        is_last = (old == K2BLK - 1);
    }
    __syncthreads();
    if (!is_last) return;
    if (tid < 64) {
        float v = (tid < K2BLK)
                    ? __hip_atomic_load(&ws2[tid], __ATOMIC_RELAXED,
                                        __HIP_MEMORY_SCOPE_AGENT)
                    : 0.f;
#pragma unroll
        for (int off = 32; off; off >>= 1)
            v += __shfl_down(v, off, 64);
        if (tid == 0) out[0] = v;
    }
}

extern "C" void kernel_launch(void* const* d_in, const int* in_sizes, int n_in,
                              void* d_out, int out_size, void* d_ws, size_t ws_size,
                              hipStream_t stream) {
    const float4* Y4 = (const float4*)d_in[0];
    float* out = (float*)d_out;
    float* P   = (float*)d_ws;                                   // 8 MB partials
    float* ws2 = (float*)((char*)d_ws + (size_t)STRIPES * D * sizeof(float));
    unsigned* counter = (unsigned*)(ws2 + K2BLK);

    hipMemsetAsync(counter, 0, sizeof(unsigned), stream);
    colsq_sweep<<<dim3(K1BLK), 256, 0, stream>>>(Y4, (float4*)P);
    col_finalize<<<dim3(K2BLK), 256, 0, stream>>>(P, ws2, counter, out);
}

// Round 6
// 195.480 us; speedup vs baseline: 1.0729x; 1.0729x over previous
//
#include <hip/hip_runtime.h>

// Y: 16384 x 2048 fp32 row-major. loss = sum_c |1 - (1/n) * sum_r Y[r][c]^2|
#define NROWS 16384
#define D     2048
#define D4    (D / 4)                       // 512 float4 per row
#define YBLOCKS 512                         // row-stripe blocks (R3 K1, best measured)
#define ROWS_PER_BLOCK (NROWS / YBLOCKS)    // 32 rows per stripe
#define K2BLK 64
// d_ws layout: P[512][2048] floats (4 MB) | ws2[64] | counter

// K1: per-column sum of squares over a 32-row stripe. grid (2,512) x 256.
// Thread owns 4 consecutive cols (1 float4), fully coalesced. Identical to
// round-3 K1 (best measured config). Thread (0,0,0) also zeroes the K2
// completion counter (plain store; visible to K2 at kernel boundary).
__global__ void __launch_bounds__(256)
colsq_partial(const float4* __restrict__ Y4, float4* __restrict__ P4,
              unsigned* __restrict__ counter) {
    if (blockIdx.x == 0 && blockIdx.y == 0 && threadIdx.x == 0)
        *counter = 0u;
    const int c4 = blockIdx.x * 256 + threadIdx.x;      // [0, 512)
    const int yb = blockIdx.y;
    const float4* p = Y4 + (size_t)yb * ROWS_PER_BLOCK * D4 + c4;
    float4 acc = make_float4(0.f, 0.f, 0.f, 0.f);
#pragma unroll 8
    for (int r = 0; r < ROWS_PER_BLOCK; ++r) {
        float4 v = p[(size_t)r * D4];
        acc.x += v.x * v.x;
        acc.y += v.y * v.y;
        acc.z += v.z * v.z;
        acc.w += v.w * v.w;
    }
    P4[(size_t)yb * D4 + c4] = acc;
}

// K2: grid 64 x 256. Block b owns cols [b*32, b*32+32); 8 threads/col
// (part = tid>>5), each sums 64 stripes. LDS-combine, |1 - s/n|, reduce the
// 32 cols, write ws2[b]; last block (counter) sums the 64 block partials
// and writes out[0]. No K3, no memset.
__global__ void __launch_bounds__(256)
col_finalize(const float* __restrict__ P, float* __restrict__ ws2,
             unsigned* __restrict__ counter, float* __restrict__ out) {
    const int tid  = threadIdx.x;
    const int col  = blockIdx.x * 32 + (tid & 31);
    const int part = tid >> 5;                          // 0..7
    float s = 0.f;
#pragma unroll 8
    for (int i = 0; i < YBLOCKS / 8; ++i) {             // 64 stripes/thread
        int yb = part * (YBLOCKS / 8) + i;
        s += P[(size_t)yb * D + col];
    }
    __shared__ float lds[256];
    lds[tid] = s;
    __syncthreads();
    if (tid < 32) {
        float tot = 0.f;
#pragma unroll
        for (int j = 0; j < 8; ++j)
            tot += lds[tid + 32 * j];
        float v = fabsf(1.0f - tot * (1.0f / (float)NROWS));
#pragma unroll
        for (int off = 16; off; off >>= 1)
            v += __shfl_down(v, off, 64);
        if (tid == 0) ws2[blockIdx.x] = v;
    }
    // completion counter: one agent-scope RMW per block (64 total)
    __threadfence();
    __shared__ int is_last;
    if (tid == 0) {
        unsigned old = __hip_atomic_fetch_add(counter, 1u, __ATOMIC_ACQ_REL,
                                              __HIP_MEMORY_SCOPE_AGENT);
        is_last = (old == K2BLK - 1);
    }
    __syncthreads();
    if (!is_last) return;
    if (tid < 64) {
        float v = __hip_atomic_load(&ws2[tid], __ATOMIC_RELAXED,
                                    __HIP_MEMORY_SCOPE_AGENT);
#pragma unroll
        for (int off = 32; off; off >>= 1)
            v += __shfl_down(v, off, 64);
        if (tid == 0) out[0] = v;
    }
}

extern "C" void kernel_launch(void* const* d_in, const int* in_sizes, int n_in,
                              void* d_out, int out_size, void* d_ws, size_t ws_size,
                              hipStream_t stream) {
    const float4* Y4 = (const float4*)d_in[0];
    float* out = (float*)d_out;
    float* P   = (float*)d_ws;                               // 4 MB partials
    float* ws2 = (float*)((char*)d_ws + (size_t)YBLOCKS * D * sizeof(float));
    unsigned* counter = (unsigned*)(ws2 + K2BLK);

    colsq_partial<<<dim3(2, YBLOCKS), 256, 0, stream>>>(Y4, (float4*)P, counter);
    col_finalize<<<dim3(K2BLK), 256, 0, stream>>>(P, ws2, counter, out);
}

// Round 8
// 184.826 us; speedup vs baseline: 1.1347x; 1.0576x over previous
//
#include <hip/hip_runtime.h>

// Y: 16384 x 2048 fp32 row-major. loss = sum_c |1 - (1/n) * sum_r Y[r][c]^2|
#define NROWS 16384
#define D     2048
#define D4    (D / 4)                       // 512 float4 per row
#define YBLOCKS 512                         // row-stripe blocks (R3/R6 K1 geometry)
#define ROWS_PER_BLOCK (NROWS / YBLOCKS)    // 32 rows per stripe
#define K2BLK 64
// d_ws layout: P[512][2048] floats (4 MB) | ws2[64] | counter

// Native 16B vector type: __builtin_nontemporal_load requires a scalar or
// native vector pointee (HIP_vector_type float4 is a struct -> rejected).
typedef float vfloat4 __attribute__((ext_vector_type(4)));

// K1: per-column sum of squares over a 32-row stripe. grid (2,512) x 256.
// Thread owns 4 consecutive cols (1 float4), fully coalesced.
// CHANGE vs R6: nontemporal loads (no L2/L3 allocation -> no dirty-ws
// evictions on the read path) + unroll 16 (more loads in flight).
__global__ void __launch_bounds__(256)
colsq_partial(const vfloat4* __restrict__ Y4, vfloat4* __restrict__ P4,
              unsigned* __restrict__ counter) {
    if (blockIdx.x == 0 && blockIdx.y == 0 && threadIdx.x == 0)
        *counter = 0u;
    const int c4 = blockIdx.x * 256 + threadIdx.x;      // [0, 512)
    const int yb = blockIdx.y;
    const vfloat4* p = Y4 + (size_t)yb * ROWS_PER_BLOCK * D4 + c4;
    vfloat4 acc = (vfloat4)(0.f);
#pragma unroll 16
    for (int r = 0; r < ROWS_PER_BLOCK; ++r) {
        vfloat4 v = __builtin_nontemporal_load(&p[(size_t)r * D4]);
        acc += v * v;
    }
    P4[(size_t)yb * D4 + c4] = acc;
}

// K2: grid 64 x 256. Block b owns cols [b*32, b*32+32); 8 threads/col,
// each sums 64 stripes. LDS-combine, |1 - s/n|, reduce 32 cols, ws2[b];
// last block (counter) sums the 64 block partials and writes out[0].
__global__ void __launch_bounds__(256)
col_finalize(const float* __restrict__ P, float* __restrict__ ws2,
             unsigned* __restrict__ counter, float* __restrict__ out) {
    const int tid  = threadIdx.x;
    const int col  = blockIdx.x * 32 + (tid & 31);
    const int part = tid >> 5;                          // 0..7
    float s = 0.f;
#pragma unroll 8
    for (int i = 0; i < YBLOCKS / 8; ++i) {             // 64 stripes/thread
        int yb = part * (YBLOCKS / 8) + i;
        s += P[(size_t)yb * D + col];
    }
    __shared__ float lds[256];
    lds[tid] = s;
    __syncthreads();
    if (tid < 32) {
        float tot = 0.f;
#pragma unroll
        for (int j = 0; j < 8; ++j)
            tot += lds[tid + 32 * j];
        float v = fabsf(1.0f - tot * (1.0f / (float)NROWS));
#pragma unroll
        for (int off = 16; off; off >>= 1)
            v += __shfl_down(v, off, 64);
        if (tid == 0) ws2[blockIdx.x] = v;
    }
    // completion counter: one agent-scope RMW per block (64 total)
    __threadfence();
    __shared__ int is_last;
    if (tid == 0) {
        unsigned old = __hip_atomic_fetch_add(counter, 1u, __ATOMIC_ACQ_REL,
                                              __HIP_MEMORY_SCOPE_AGENT);
        is_last = (old == K2BLK - 1);
    }
    __syncthreads();
    if (!is_last) return;
    if (tid < 64) {
        float v = __hip_atomic_load(&ws2[tid], __ATOMIC_RELAXED,
                                    __HIP_MEMORY_SCOPE_AGENT);
#pragma unroll
        for (int off = 32; off; off >>= 1)
            v += __shfl_down(v, off, 64);
        if (tid == 0) out[0] = v;
    }
}

extern "C" void kernel_launch(void* const* d_in, const int* in_sizes, int n_in,
                              void* d_out, int out_size, void* d_ws, size_t ws_size,
                              hipStream_t stream) {
    const vfloat4* Y4 = (const vfloat4*)d_in[0];
    float* out = (float*)d_out;
    float* P   = (float*)d_ws;                               // 4 MB partials
    float* ws2 = (float*)((char*)d_ws + (size_t)YBLOCKS * D * sizeof(float));
    unsigned* counter = (unsigned*)(ws2 + K2BLK);

    colsq_partial<<<dim3(2, YBLOCKS), 256, 0, stream>>>(Y4, (vfloat4*)P, counter);
    col_finalize<<<dim3(K2BLK), 256, 0, stream>>>(P, ws2, counter, out);
}